// Round 9
// baseline (856.708 us; speedup 1.0000x reference)
//
#include <hip/hip_runtime.h>

typedef float f32x4 __attribute__((ext_vector_type(4)));
typedef __bf16 bf16x8 __attribute__((ext_vector_type(8)));

#define NSTAGE 20
#define TSEQ   2048
#define NST    128
#define NP2    256
#define NCLS   202

static __device__ __forceinline__ unsigned short f2b(float f) {
  return __builtin_bit_cast(unsigned short, (__bf16)f);
}

// ---------------------------------------------------------------------------
// Kernel 1: convert weights to bf16 in ws (verified).
//  Wt   [64][2048]  = W_embed^T
//  Bws  [20][256][64]: row n'=2n+p holds B_{re/im}[s][n][k] along k
//  Cws  [20][64][256]: row d holds (C_re[s][d][n], -C_im[s][d][n]) interleaved
//  Wclst[208][64]   = W_cls^T, rows >=202 zero
// ---------------------------------------------------------------------------
__global__ void lru_convert_kernel(const float* __restrict__ Wemb,
                                   const float* __restrict__ Bre, const float* __restrict__ Bim,
                                   const float* __restrict__ Cre, const float* __restrict__ Cim,
                                   const float* __restrict__ Wcls,
                                   unsigned short* __restrict__ Wt,
                                   unsigned short* __restrict__ Bws,
                                   unsigned short* __restrict__ Cws,
                                   unsigned short* __restrict__ Wclst)
{
  const int NWT = 64 * 2048;
  const int NB  = NSTAGE * NP2 * 64;
  const int NC  = NSTAGE * 64 * NP2;
  const int NWC = 208 * 64;
  int idx = blockIdx.x * 256 + threadIdx.x;
  if (idx < NWT) {
    int d = idx >> 11, k = idx & 2047;
    Wt[idx] = f2b(Wemb[k * 64 + d]);
  } else if (idx < NWT + NB) {
    int r = idx - NWT;
    int s = r / (NP2 * 64); int r2 = r % (NP2 * 64);
    int np = r2 >> 6, k = r2 & 63;
    int n = np >> 1, p = np & 1;
    float v = p ? Bim[(s * NST + n) * 64 + k] : Bre[(s * NST + n) * 64 + k];
    Bws[r] = f2b(v);
  } else if (idx < NWT + NB + NC) {
    int r = idx - NWT - NB;
    int s = r / (64 * NP2); int r2 = r % (64 * NP2);
    int d = r2 >> 8, np = r2 & 255;
    int n = np >> 1, p = np & 1;
    float v = p ? -Cim[(s * 64 + d) * NST + n] : Cre[(s * 64 + d) * NST + n];
    Cws[r] = f2b(v);
  } else if (idx < NWT + NB + NC + NWC) {
    int r = idx - NWT - NB - NC;
    int cls = r >> 6, k = r & 63;
    Wclst[r] = (cls < NCLS) ? f2b(Wcls[k * NCLS + cls]) : (unsigned short)0;
  }
}

// ---------------------------------------------------------------------------
// Kernel 2: LN0 + embed GEMM + stage-0 carry. 1024 blocks x 256 threads,
// 16-token tiles. GEMM builds MFMA A-fragments DIRECTLY from global x with
// LN applied on the fly (no LDS staging, no barriers in the kc loop).
// The h tile stays in LDS; the stage-0 carry (LN + B-proj + 16-step scan)
// is computed before exit. h0 also written to global for the stage loop.
// ---------------------------------------------------------------------------
__launch_bounds__(256)
__global__ void lru_embed_kernel(const float* __restrict__ x,
                                 const float* __restrict__ g0,
                                 const float* __restrict__ b0,
                                 const unsigned short* __restrict__ Wt,
                                 const float* __restrict__ bemb,
                                 const unsigned short* __restrict__ Bws,
                                 const float* __restrict__ lng,
                                 const float* __restrict__ lnb,
                                 const float* __restrict__ nulog,
                                 const float* __restrict__ thlog,
                                 const float* __restrict__ gmlog,
                                 float* __restrict__ h0,
                                 float* __restrict__ carr)
{
  __shared__ float mu_s[16], rs_s[16];
  __shared__ float hs[16][68];
  __shared__ __align__(16) unsigned short zb[16][72];
  __shared__ __align__(16) float ucat[16][264];

  const int tid = threadIdx.x;
  const int b  = blockIdx.x >> 7;
  const int c  = blockIdx.x & 127;
  const int t0 = c * 16;
  const int w = tid >> 6, lane = tid & 63;
  const int cl = lane & 15, q = lane >> 4;
  const int tg = tid >> 4, g = tid & 15;

  // LN0 statistics: wave w -> tokens 4w..4w+3 (coalesced HBM read of x)
  for (int i = 0; i < 4; ++i) {
    int t = w * 4 + i;
    const float* xp = x + ((size_t)(b * TSEQ + t0 + t)) * 2048;
    float sum = 0.f, sq = 0.f;
    #pragma unroll
    for (int j = 0; j < 32; ++j) {
      float v = xp[lane + 64 * j];
      sum += v; sq += v * v;
    }
    #pragma unroll
    for (int m = 1; m < 64; m <<= 1) {
      sum += __shfl_xor(sum, m); sq += __shfl_xor(sq, m);
    }
    if (lane == 0) {
      float mu = sum * (1.f / 2048.f);
      float var = sq * (1.f / 2048.f) - mu * mu;
      mu_s[t] = mu;
      rs_s[t] = rsqrtf(var + 1e-5f);
    }
  }
  __syncthreads();

  // embed GEMM, barrier-free: lane (cl,q) = token cl, k-slice q*8
  {
    const float muT = mu_s[cl], rsT = rs_s[cl];
    const float* xrow = x + ((size_t)(b * TSEQ + t0 + cl)) * 2048;
    const unsigned short* wrow = Wt + ((size_t)(w * 16 + cl)) * 2048;
    f32x4 acc = {0.f, 0.f, 0.f, 0.f};
    for (int kc = 0; kc < 32; ++kc) {
      #pragma unroll
      for (int ks = 0; ks < 2; ++ks) {
        int ko = kc * 64 + ks * 32 + q * 8;
        float4 xa = *(const float4*)&xrow[ko];
        float4 xb = *(const float4*)&xrow[ko + 4];
        float4 ga = *(const float4*)&g0[ko];
        float4 gb = *(const float4*)&g0[ko + 4];
        float4 ba = *(const float4*)&b0[ko];
        float4 bb = *(const float4*)&b0[ko + 4];
        float z0 = (xa.x - muT) * rsT * ga.x + ba.x;
        float z1 = (xa.y - muT) * rsT * ga.y + ba.y;
        float z2 = (xa.z - muT) * rsT * ga.z + ba.z;
        float z3 = (xa.w - muT) * rsT * ga.w + ba.w;
        float z4 = (xb.x - muT) * rsT * gb.x + bb.x;
        float z5 = (xb.y - muT) * rsT * gb.y + bb.y;
        float z6 = (xb.z - muT) * rsT * gb.z + bb.z;
        float z7 = (xb.w - muT) * rsT * gb.w + bb.w;
        uint4 u;
        u.x = (unsigned)f2b(z0) | ((unsigned)f2b(z1) << 16);
        u.y = (unsigned)f2b(z2) | ((unsigned)f2b(z3) << 16);
        u.z = (unsigned)f2b(z4) | ((unsigned)f2b(z5) << 16);
        u.w = (unsigned)f2b(z6) | ((unsigned)f2b(z7) << 16);
        bf16x8 a = __builtin_bit_cast(bf16x8, u);
        bf16x8 wv = *(const bf16x8*)&wrow[ko];
        acc = __builtin_amdgcn_mfma_f32_16x16x32_bf16(a, wv, acc, 0, 0, 0);
      }
    }
    int d = w * 16 + cl;
    float be = bemb[d];
    #pragma unroll
    for (int r = 0; r < 4; ++r) {
      float hv = acc[r] + be;
      hs[q * 4 + r][d] = hv;
      h0[((size_t)(b * TSEQ + t0 + q * 4 + r)) * 64 + d] = hv;
    }
  }
  __syncthreads();

  // stage-0 carry: LN from hs
  {
    float4 hv = *(const float4*)&hs[tg][g * 4];
    float sum = hv.x + hv.y + hv.z + hv.w;
    sum += __shfl_xor(sum, 1); sum += __shfl_xor(sum, 2);
    sum += __shfl_xor(sum, 4); sum += __shfl_xor(sum, 8);
    float mu = sum * (1.f / 64.f);
    float d0 = hv.x - mu, d1 = hv.y - mu, d2 = hv.z - mu, d3 = hv.w - mu;
    float sq = d0 * d0 + d1 * d1 + d2 * d2 + d3 * d3;
    sq += __shfl_xor(sq, 1); sq += __shfl_xor(sq, 2);
    sq += __shfl_xor(sq, 4); sq += __shfl_xor(sq, 8);
    float rs = rsqrtf(sq * (1.f / 64.f) + 1e-5f);
    float4 gv = *(const float4*)&lng[g * 4];
    float4 bv = *(const float4*)&lnb[g * 4];
    float z0 = d0 * rs * gv.x + bv.x;
    float z1 = d1 * rs * gv.y + bv.y;
    float z2 = d2 * rs * gv.z + bv.z;
    float z3 = d3 * rs * gv.w + bv.w;
    *(unsigned*)&zb[tg][g * 4]     = (unsigned)f2b(z0) | ((unsigned)f2b(z1) << 16);
    *(unsigned*)&zb[tg][g * 4 + 2] = (unsigned)f2b(z2) | ((unsigned)f2b(z3) << 16);
  }
  __syncthreads();

  // B-proj (stage 0)
  {
    bf16x8 a0 = *(const bf16x8*)((const char*)&zb[0][0] + cl * 144 + q * 16);
    bf16x8 a1 = *(const bf16x8*)((const char*)&zb[0][0] + cl * 144 + 64 + q * 16);
    #pragma unroll
    for (int ti = 0; ti < 4; ++ti) {
      int np0 = (w * 4 + ti) * 16;
      const unsigned short* bp = Bws + (np0 + cl) * 64 + q * 8;
      bf16x8 b0v = *(const bf16x8*)bp;
      bf16x8 b1v = *(const bf16x8*)(bp + 32);
      f32x4 acc = {0.f, 0.f, 0.f, 0.f};
      acc = __builtin_amdgcn_mfma_f32_16x16x32_bf16(a0, b0v, acc, 0, 0, 0);
      acc = __builtin_amdgcn_mfma_f32_16x16x32_bf16(a1, b1v, acc, 0, 0, 0);
      int np = np0 + cl;
      float gam = __expf(gmlog[np >> 1]);
      ucat[q * 4 + 0][np] = acc[0] * gam;
      ucat[q * 4 + 1][np] = acc[1] * gam;
      ucat[q * 4 + 2][np] = acc[2] * gam;
      ucat[q * 4 + 3][np] = acc[3] * gam;
    }
  }
  __syncthreads();

  // local 16-step scan -> carry for stage 0
  if (tid < NST) {
    int n = tid;
    float mag = __expf(-__expf(nulog[n]));
    float th  = __expf(thlog[n]);
    float lamr = mag * __cosf(th);
    float lami = mag * __sinf(th);
    float hr = 0.f, hi = 0.f;
    #pragma unroll
    for (int t = 0; t < 16; ++t) {
      float ur = ucat[t][2 * n], ui = ucat[t][2 * n + 1];
      float nr = fmaf(lamr, hr, fmaf(-lami, hi, ur));
      float ni = fmaf(lamr, hi, fmaf(lami, hr, ui));
      hr = nr; hi = ni;
    }
    float* cw = carr + ((size_t)(b * 128 + c)) * 256 + 2 * n;
    cw[0] = hr;
    cw[1] = hi;
  }
}

// ---------------------------------------------------------------------------
// Kernel 3: apply stage s + carry stage s+1. 16-token chunks, grid 1024
// (4 blocks/CU). Pass 1: lookback prefix (lam^16, <=127 chunks) -> seeded
// scan -> C-proj -> h update in LDS. Pass 2: LN(s+1) + B-proj(s+1) + scan
// of updated h -> carrout; h0 writeback. Last stage: classifier.
// ---------------------------------------------------------------------------
__launch_bounds__(256)
__global__ void lru_applycarry_kernel(float* __restrict__ h0,
                                      const float* __restrict__ carrin,
                                      float* __restrict__ carrout,
                                      const unsigned short* __restrict__ Bws,
                                      const unsigned short* __restrict__ Cws,
                                      const float* __restrict__ lng,
                                      const float* __restrict__ lnb,
                                      const float* __restrict__ nulog,
                                      const float* __restrict__ thlog,
                                      const float* __restrict__ gmlog,
                                      const float* __restrict__ dskip,
                                      int s, int last,
                                      const unsigned short* __restrict__ Wclst,
                                      const float* __restrict__ bcls,
                                      float* __restrict__ out)
{
  __shared__ float hs[16][68];
  __shared__ float zsm[16][68];
  __shared__ __align__(16) unsigned short zb[16][72];
  __shared__ __align__(16) float ucat[16][264];
  __shared__ __align__(16) unsigned short hcb[16][264];

  const int tid = threadIdx.x;
  const int b = blockIdx.x >> 7;
  const int c = blockIdx.x & 127;
  const int t0 = c * 16;
  const int w = tid >> 6, lane = tid & 63;
  const int cl = lane & 15, q = lane >> 4;
  const int tg = tid >> 4, g = tid & 15;

  // lambda(s), lam^16, prefix over earlier chunks (dispatch-boundary coherent)
  float lamr = 0.f, lami = 0.f, Pr = 0.f, Pi = 0.f;
  if (tid < NST) {
    int n = tid;
    float mag = __expf(-__expf(nulog[s * NST + n]));
    float th  = __expf(thlog[s * NST + n]);
    lamr = mag * __cosf(th);
    lami = mag * __sinf(th);
    float ar = lamr, ai = lami;
    #pragma unroll
    for (int it = 0; it < 4; ++it) {     // lam^16
      float nr = ar * ar - ai * ai;
      float ni = 2.f * ar * ai;
      ar = nr; ai = ni;
    }
    const float* cb = carrin + (size_t)b * 128 * 256 + 2 * n;
    #pragma unroll 4
    for (int j = 0; j < c; ++j) {
      float cr = cb[j * 256];
      float ci = cb[j * 256 + 1];
      float nr = fmaf(ar, Pr, fmaf(-ai, Pi, cr));
      float ni = fmaf(ar, Pi, fmaf(ai, Pr, ci));
      Pr = nr; Pi = ni;
    }
  }

  // pass 1: load h + LN(s)
  {
    float4 hv = *(const float4*)&h0[((size_t)(b * TSEQ + t0 + tg)) * 64 + g * 4];
    hs[tg][g * 4 + 0] = hv.x; hs[tg][g * 4 + 1] = hv.y;
    hs[tg][g * 4 + 2] = hv.z; hs[tg][g * 4 + 3] = hv.w;
    float sum = hv.x + hv.y + hv.z + hv.w;
    sum += __shfl_xor(sum, 1); sum += __shfl_xor(sum, 2);
    sum += __shfl_xor(sum, 4); sum += __shfl_xor(sum, 8);
    float mu = sum * (1.f / 64.f);
    float d0 = hv.x - mu, d1 = hv.y - mu, d2 = hv.z - mu, d3 = hv.w - mu;
    float sq = d0 * d0 + d1 * d1 + d2 * d2 + d3 * d3;
    sq += __shfl_xor(sq, 1); sq += __shfl_xor(sq, 2);
    sq += __shfl_xor(sq, 4); sq += __shfl_xor(sq, 8);
    float rs = rsqrtf(sq * (1.f / 64.f) + 1e-5f);
    float4 gv = *(const float4*)&lng[s * 64 + g * 4];
    float4 bv = *(const float4*)&lnb[s * 64 + g * 4];
    float z0 = d0 * rs * gv.x + bv.x;
    float z1 = d1 * rs * gv.y + bv.y;
    float z2 = d2 * rs * gv.z + bv.z;
    float z3 = d3 * rs * gv.w + bv.w;
    zsm[tg][g * 4 + 0] = z0; zsm[tg][g * 4 + 1] = z1;
    zsm[tg][g * 4 + 2] = z2; zsm[tg][g * 4 + 3] = z3;
    *(unsigned*)&zb[tg][g * 4]     = (unsigned)f2b(z0) | ((unsigned)f2b(z1) << 16);
    *(unsigned*)&zb[tg][g * 4 + 2] = (unsigned)f2b(z2) | ((unsigned)f2b(z3) << 16);
  }
  __syncthreads();

  // B-proj (stage s)
  {
    bf16x8 a0 = *(const bf16x8*)((const char*)&zb[0][0] + cl * 144 + q * 16);
    bf16x8 a1 = *(const bf16x8*)((const char*)&zb[0][0] + cl * 144 + 64 + q * 16);
    const unsigned short* bb = Bws + (size_t)s * NP2 * 64;
    #pragma unroll
    for (int ti = 0; ti < 4; ++ti) {
      int np0 = (w * 4 + ti) * 16;
      const unsigned short* bp = bb + (np0 + cl) * 64 + q * 8;
      bf16x8 b0v = *(const bf16x8*)bp;
      bf16x8 b1v = *(const bf16x8*)(bp + 32);
      f32x4 acc = {0.f, 0.f, 0.f, 0.f};
      acc = __builtin_amdgcn_mfma_f32_16x16x32_bf16(a0, b0v, acc, 0, 0, 0);
      acc = __builtin_amdgcn_mfma_f32_16x16x32_bf16(a1, b1v, acc, 0, 0, 0);
      int np = np0 + cl;
      float gam = __expf(gmlog[s * NST + (np >> 1)]);
      ucat[q * 4 + 0][np] = acc[0] * gam;
      ucat[q * 4 + 1][np] = acc[1] * gam;
      ucat[q * 4 + 2][np] = acc[2] * gam;
      ucat[q * 4 + 3][np] = acc[3] * gam;
    }
  }
  __syncthreads();

  // seeded 16-step scan (global h values directly) -> hcb (bf16)
  if (tid < NST) {
    int n = tid;
    float hr = Pr, hi = Pi;
    #pragma unroll
    for (int t = 0; t < 16; ++t) {
      float ur = ucat[t][2 * n], ui = ucat[t][2 * n + 1];
      float nr = fmaf(lamr, hr, fmaf(-lami, hi, ur));
      float ni = fmaf(lamr, hi, fmaf(lami, hr, ui));
      hr = nr; hi = ni;
      *(unsigned*)&hcb[t][2 * n] = (unsigned)f2b(hr) | ((unsigned)f2b(hi) << 16);
    }
  }
  __syncthreads();

  // C-proj (K=256); h += y + Dskip*z (in LDS)
  {
    int d0 = w * 16;
    const unsigned short* cp = Cws + ((size_t)s * 64 + d0 + cl) * NP2 + q * 8;
    f32x4 acc = {0.f, 0.f, 0.f, 0.f};
    #pragma unroll
    for (int ks = 0; ks < 8; ++ks) {
      bf16x8 a  = *(const bf16x8*)((const char*)&hcb[0][0] + cl * 528 + ks * 64 + q * 16);
      bf16x8 cc = *(const bf16x8*)(cp + ks * 32);
      acc = __builtin_amdgcn_mfma_f32_16x16x32_bf16(a, cc, acc, 0, 0, 0);
    }
    int d = d0 + cl;
    float dk = dskip[s * 64 + d];
    #pragma unroll
    for (int r = 0; r < 4; ++r) {
      int t = q * 4 + r;
      hs[t][d] = hs[t][d] + acc[r] + dk * zsm[t][d];
    }
  }
  __syncthreads();

  if (!last) {
    const int s1 = s + 1;
    // pass 2: LN(s+1) from updated hs
    {
      float4 hv = *(const float4*)&hs[tg][g * 4];
      float sum = hv.x + hv.y + hv.z + hv.w;
      sum += __shfl_xor(sum, 1); sum += __shfl_xor(sum, 2);
      sum += __shfl_xor(sum, 4); sum += __shfl_xor(sum, 8);
      float mu = sum * (1.f / 64.f);
      float d0 = hv.x - mu, d1 = hv.y - mu, d2 = hv.z - mu, d3 = hv.w - mu;
      float sq = d0 * d0 + d1 * d1 + d2 * d2 + d3 * d3;
      sq += __shfl_xor(sq, 1); sq += __shfl_xor(sq, 2);
      sq += __shfl_xor(sq, 4); sq += __shfl_xor(sq, 8);
      float rs = rsqrtf(sq * (1.f / 64.f) + 1e-5f);
      float4 gv = *(const float4*)&lng[s1 * 64 + g * 4];
      float4 bv = *(const float4*)&lnb[s1 * 64 + g * 4];
      float z0 = d0 * rs * gv.x + bv.x;
      float z1 = d1 * rs * gv.y + bv.y;
      float z2 = d2 * rs * gv.z + bv.z;
      float z3 = d3 * rs * gv.w + bv.w;
      *(unsigned*)&zb[tg][g * 4]     = (unsigned)f2b(z0) | ((unsigned)f2b(z1) << 16);
      *(unsigned*)&zb[tg][g * 4 + 2] = (unsigned)f2b(z2) | ((unsigned)f2b(z3) << 16);
    }
    __syncthreads();
    // B-proj (stage s+1)
    {
      bf16x8 a0 = *(const bf16x8*)((const char*)&zb[0][0] + cl * 144 + q * 16);
      bf16x8 a1 = *(const bf16x8*)((const char*)&zb[0][0] + cl * 144 + 64 + q * 16);
      const unsigned short* bb = Bws + (size_t)s1 * NP2 * 64;
      #pragma unroll
      for (int ti = 0; ti < 4; ++ti) {
        int np0 = (w * 4 + ti) * 16;
        const unsigned short* bp = bb + (np0 + cl) * 64 + q * 8;
        bf16x8 b0v = *(const bf16x8*)bp;
        bf16x8 b1v = *(const bf16x8*)(bp + 32);
        f32x4 acc = {0.f, 0.f, 0.f, 0.f};
        acc = __builtin_amdgcn_mfma_f32_16x16x32_bf16(a0, b0v, acc, 0, 0, 0);
        acc = __builtin_amdgcn_mfma_f32_16x16x32_bf16(a1, b1v, acc, 0, 0, 0);
        int np = np0 + cl;
        float gam = __expf(gmlog[s1 * NST + (np >> 1)]);
        ucat[q * 4 + 0][np] = acc[0] * gam;
        ucat[q * 4 + 1][np] = acc[1] * gam;
        ucat[q * 4 + 2][np] = acc[2] * gam;
        ucat[q * 4 + 3][np] = acc[3] * gam;
      }
    }
    __syncthreads();
    // carry scan (s+1) + h0 writeback (independent work, overlaps)
    if (tid < NST) {
      int n = tid;
      float mag = __expf(-__expf(nulog[s1 * NST + n]));
      float th  = __expf(thlog[s1 * NST + n]);
      float l2r = mag * __cosf(th);
      float l2i = mag * __sinf(th);
      float hr = 0.f, hi = 0.f;
      #pragma unroll
      for (int t = 0; t < 16; ++t) {
        float ur = ucat[t][2 * n], ui = ucat[t][2 * n + 1];
        float nr = fmaf(l2r, hr, fmaf(-l2i, hi, ur));
        float ni = fmaf(l2r, hi, fmaf(l2i, hr, ui));
        hr = nr; hi = ni;
      }
      float* cw = carrout + ((size_t)(b * 128 + c)) * 256 + 2 * n;
      cw[0] = hr;
      cw[1] = hi;
    }
    {
      float4 hv;
      hv.x = hs[tg][g * 4 + 0]; hv.y = hs[tg][g * 4 + 1];
      hv.z = hs[tg][g * 4 + 2]; hv.w = hs[tg][g * 4 + 3];
      *(float4*)&h0[((size_t)(b * TSEQ + t0 + tg)) * 64 + g * 4] = hv;
    }
  } else {
    // classifier from updated hs
    {
      *(unsigned*)&zb[tg][g * 4] =
          (unsigned)f2b(hs[tg][g * 4 + 0]) | ((unsigned)f2b(hs[tg][g * 4 + 1]) << 16);
      *(unsigned*)&zb[tg][g * 4 + 2] =
          (unsigned)f2b(hs[tg][g * 4 + 2]) | ((unsigned)f2b(hs[tg][g * 4 + 3]) << 16);
    }
    __syncthreads();
    bf16x8 a0 = *(const bf16x8*)((const char*)&zb[0][0] + cl * 144 + q * 16);
    bf16x8 a1 = *(const bf16x8*)((const char*)&zb[0][0] + cl * 144 + 64 + q * 16);
    for (int ti = w; ti < 13; ti += 4) {
      int cls0 = ti * 16;
      const unsigned short* wp = Wclst + (cls0 + cl) * 64 + q * 8;
      bf16x8 b0v = *(const bf16x8*)wp;
      bf16x8 b1v = *(const bf16x8*)(wp + 32);
      f32x4 acc = {0.f, 0.f, 0.f, 0.f};
      acc = __builtin_amdgcn_mfma_f32_16x16x32_bf16(a0, b0v, acc, 0, 0, 0);
      acc = __builtin_amdgcn_mfma_f32_16x16x32_bf16(a1, b1v, acc, 0, 0, 0);
      int cls = cls0 + cl;
      if (cls < NCLS) {
        float bc = bcls[cls];
        #pragma unroll
        for (int r = 0; r < 4; ++r) {
          int t = q * 4 + r;
          out[((size_t)(b * TSEQ + t0 + t)) * NCLS + cls] = acc[r] + bc;
        }
      }
    }
  }
}

// ---------------------------------------------------------------------------
extern "C" void kernel_launch(void* const* d_in, const int* in_sizes, int n_in,
                              void* d_out, int out_size, void* d_ws, size_t ws_size,
                              hipStream_t stream) {
  (void)in_sizes; (void)n_in; (void)out_size; (void)ws_size;
  const float* x     = (const float*)d_in[0];
  const float* ln0g  = (const float*)d_in[1];
  const float* ln0b  = (const float*)d_in[2];
  const float* Wemb  = (const float*)d_in[3];
  const float* bemb  = (const float*)d_in[4];
  const float* lng   = (const float*)d_in[5];
  const float* lnb   = (const float*)d_in[6];
  const float* nulog = (const float*)d_in[7];
  const float* thlog = (const float*)d_in[8];
  const float* gmlog = (const float*)d_in[9];
  const float* Bre   = (const float*)d_in[10];
  const float* Bim   = (const float*)d_in[11];
  const float* Cre   = (const float*)d_in[12];
  const float* Cim   = (const float*)d_in[13];
  const float* dskip = (const float*)d_in[14];
  const float* Wcls  = (const float*)d_in[15];
  const float* bcls  = (const float*)d_in[16];
  float* out = (float*)d_out;

  char* ws = (char*)d_ws;
  // ws layout (bytes):
  //  carrA @0       : 8*128*256*4 = 1048576
  //  carrB @1048576 : 1048576
  //  Bws   @2097152 : 20*256*64*2 = 655360
  //  Cws   @2752512 : 655360
  //  Wt    @3407872 : 64*2048*2  = 262144
  //  Wclst @3670016 : 208*64*2   = 26624
  //  h0    @3696640 : 16384*64*4 = 4194304  (end 7890944)
  float* carrA         = (float*)(ws + 0);
  float* carrB         = (float*)(ws + 1048576);
  unsigned short* Bws  = (unsigned short*)(ws + 2097152);
  unsigned short* Cws  = (unsigned short*)(ws + 2752512);
  unsigned short* Wt   = (unsigned short*)(ws + 3407872);
  unsigned short* Wcl  = (unsigned short*)(ws + 3670016);
  float* h0            = (float*)(ws + 3696640);

  lru_convert_kernel<<<3124, 256, 0, stream>>>(Wemb, Bre, Bim, Cre, Cim, Wcls,
                                               Wt, Bws, Cws, Wcl);
  lru_embed_kernel<<<1024, 256, 0, stream>>>(x, ln0g, ln0b, Wt, bemb, Bws,
                                             lng, lnb, nulog, thlog, gmlog,
                                             h0, carrA);
  for (int s = 0; s < NSTAGE; ++s) {
    float* cin  = (s & 1) ? carrB : carrA;
    float* cout = (s & 1) ? carrA : carrB;
    lru_applycarry_kernel<<<1024, 256, 0, stream>>>(h0, cin, cout, Bws, Cws,
                                                    lng, lnb, nulog, thlog,
                                                    gmlog, dskip, s,
                                                    (s == NSTAGE - 1) ? 1 : 0,
                                                    Wcl, bcls, out);
  }
}

// Round 10
// 766.435 us; speedup vs baseline: 1.1178x; 1.1178x over previous
//
#include <hip/hip_runtime.h>

typedef float f32x4 __attribute__((ext_vector_type(4)));
typedef __bf16 bf16x8 __attribute__((ext_vector_type(8)));

#define NSTAGE 20
#define TSEQ   2048
#define NST    128
#define NP2    256
#define NCLS   202
#define NCHUNK 32          // 64-token chunks per sequence
#define CHTOK  64

static __device__ __forceinline__ unsigned short f2b(float f) {
  return __builtin_bit_cast(unsigned short, (__bf16)f);
}

// ---------------------------------------------------------------------------
// Kernel 1: convert weights to bf16 in ws (verified).
// ---------------------------------------------------------------------------
__global__ void lru_convert_kernel(const float* __restrict__ Wemb,
                                   const float* __restrict__ Bre, const float* __restrict__ Bim,
                                   const float* __restrict__ Cre, const float* __restrict__ Cim,
                                   const float* __restrict__ Wcls,
                                   unsigned short* __restrict__ Wt,
                                   unsigned short* __restrict__ Bws,
                                   unsigned short* __restrict__ Cws,
                                   unsigned short* __restrict__ Wclst)
{
  const int NWT = 64 * 2048;
  const int NB  = NSTAGE * NP2 * 64;
  const int NC  = NSTAGE * 64 * NP2;
  const int NWC = 208 * 64;
  int idx = blockIdx.x * 256 + threadIdx.x;
  if (idx < NWT) {
    int d = idx >> 11, k = idx & 2047;
    Wt[idx] = f2b(Wemb[k * 64 + d]);
  } else if (idx < NWT + NB) {
    int r = idx - NWT;
    int s = r / (NP2 * 64); int r2 = r % (NP2 * 64);
    int np = r2 >> 6, k = r2 & 63;
    int n = np >> 1, p = np & 1;
    float v = p ? Bim[(s * NST + n) * 64 + k] : Bre[(s * NST + n) * 64 + k];
    Bws[r] = f2b(v);
  } else if (idx < NWT + NB + NC) {
    int r = idx - NWT - NB;
    int s = r / (64 * NP2); int r2 = r % (64 * NP2);
    int d = r2 >> 8, np = r2 & 255;
    int n = np >> 1, p = np & 1;
    float v = p ? -Cim[(s * 64 + d) * NST + n] : Cre[(s * 64 + d) * NST + n];
    Cws[r] = f2b(v);
  } else if (idx < NWT + NB + NC + NWC) {
    int r = idx - NWT - NB - NC;
    int cls = r >> 6, k = r & 63;
    Wclst[r] = (cls < NCLS) ? f2b(Wcls[k * NCLS + cls]) : (unsigned short)0;
  }
}

// ---------------------------------------------------------------------------
// Kernel 2: LN0 + embed GEMM, 1024 blocks x 256 threads, 16-token tiles.
// LDS-staged (R8-proven) with: float4-vectorized stats, 128-float staging
// chunks (16 iterations, 32 barriers instead of 64).
// ---------------------------------------------------------------------------
__launch_bounds__(256)
__global__ void lru_embed_kernel(const float* __restrict__ x,
                                 const float* __restrict__ g0,
                                 const float* __restrict__ b0,
                                 const unsigned short* __restrict__ Wt,
                                 const float* __restrict__ bemb,
                                 float* __restrict__ h0)
{
  __shared__ __align__(16) unsigned short zb[16][136];   // 272 B stride
  __shared__ float mu_s[16], rs_s[16];

  const int tid = threadIdx.x;
  const int b  = blockIdx.x >> 7;
  const int t0 = (blockIdx.x & 127) * 16;
  const int w = tid >> 6, lane = tid & 63;
  const int cl = lane & 15, q = lane >> 4;
  const int tg = tid >> 4, g = tid & 15;

  // LN0 statistics, float4-vectorized: wave w -> tokens 4w..4w+3
  for (int i = 0; i < 4; ++i) {
    int t = w * 4 + i;
    const float* xp = x + ((size_t)(b * TSEQ + t0 + t)) * 2048;
    float sum = 0.f, sq = 0.f;
    #pragma unroll
    for (int j = 0; j < 8; ++j) {
      float4 v = *(const float4*)&xp[lane * 4 + 256 * j];
      sum += v.x + v.y + v.z + v.w;
      sq  += v.x * v.x + v.y * v.y + v.z * v.z + v.w * v.w;
    }
    #pragma unroll
    for (int m = 1; m < 64; m <<= 1) {
      sum += __shfl_xor(sum, m); sq += __shfl_xor(sq, m);
    }
    if (lane == 0) {
      float mu = sum * (1.f / 2048.f);
      float var = sq * (1.f / 2048.f) - mu * mu;
      mu_s[t] = mu;
      rs_s[t] = rsqrtf(var + 1e-5f);
    }
  }
  __syncthreads();

  // embed GEMM: 16 staging iterations of 128 floats; 4 MFMA each
  {
    const float muT = mu_s[tg], rsT = rs_s[tg];
    f32x4 acc = {0.f, 0.f, 0.f, 0.f};
    for (int kc = 0; kc < 16; ++kc) {
      __syncthreads();
      {
        const float* xp = x + ((size_t)(b * TSEQ + t0 + tg)) * 2048 + kc * 128 + g * 8;
        float4 xa = *(const float4*)xp;
        float4 xb = *(const float4*)(xp + 4);
        float4 ga = *(const float4*)&g0[kc * 128 + g * 8];
        float4 gb = *(const float4*)&g0[kc * 128 + g * 8 + 4];
        float4 ba = *(const float4*)&b0[kc * 128 + g * 8];
        float4 bb = *(const float4*)&b0[kc * 128 + g * 8 + 4];
        float z0 = (xa.x - muT) * rsT * ga.x + ba.x;
        float z1 = (xa.y - muT) * rsT * ga.y + ba.y;
        float z2 = (xa.z - muT) * rsT * ga.z + ba.z;
        float z3 = (xa.w - muT) * rsT * ga.w + ba.w;
        float z4 = (xb.x - muT) * rsT * gb.x + bb.x;
        float z5 = (xb.y - muT) * rsT * gb.y + bb.y;
        float z6 = (xb.z - muT) * rsT * gb.z + bb.z;
        float z7 = (xb.w - muT) * rsT * gb.w + bb.w;
        uint4 u;
        u.x = (unsigned)f2b(z0) | ((unsigned)f2b(z1) << 16);
        u.y = (unsigned)f2b(z2) | ((unsigned)f2b(z3) << 16);
        u.z = (unsigned)f2b(z4) | ((unsigned)f2b(z5) << 16);
        u.w = (unsigned)f2b(z6) | ((unsigned)f2b(z7) << 16);
        *(uint4*)((char*)&zb[0][0] + tg * 272 + g * 16) = u;
      }
      __syncthreads();
      #pragma unroll
      for (int ks = 0; ks < 4; ++ks) {
        bf16x8 a = *(const bf16x8*)((const char*)&zb[0][0] + cl * 272 + ks * 64 + q * 16);
        const unsigned short* wp = Wt + ((size_t)(w * 16 + cl)) * 2048 + kc * 128 + ks * 32 + q * 8;
        bf16x8 wv = *(const bf16x8*)wp;
        acc = __builtin_amdgcn_mfma_f32_16x16x32_bf16(a, wv, acc, 0, 0, 0);
      }
    }
    int d = w * 16 + cl;
    float be = bemb[d];
    #pragma unroll
    for (int r = 0; r < 4; ++r)
      h0[((size_t)(b * TSEQ + t0 + q * 4 + r)) * 64 + d] = acc[r] + be;
  }
}

// ---------------------------------------------------------------------------
// Kernel 3: stage-0 carry (R8 verbatim). Block (b,c) owns 64 tokens.
// ---------------------------------------------------------------------------
__launch_bounds__(256)
__global__ void lru_carry0_kernel(const float* __restrict__ h0,
                                  const unsigned short* __restrict__ Bws,
                                  const float* __restrict__ lng,
                                  const float* __restrict__ lnb,
                                  const float* __restrict__ nulog,
                                  const float* __restrict__ thlog,
                                  const float* __restrict__ gmlog,
                                  float* __restrict__ carr)
{
  __shared__ __align__(16) unsigned short zb[16][72];
  __shared__ __align__(16) float ucat[16][264];

  const int tid = threadIdx.x;
  const int b = blockIdx.x >> 5;
  const int c = blockIdx.x & 31;
  const int t0 = c * CHTOK;
  const int w = tid >> 6, lane = tid & 63;
  const int cl = lane & 15, q = lane >> 4;
  const int tg = tid >> 4, g = tid & 15;

  float lamr = 0.f, lami = 0.f, hr = 0.f, hi = 0.f;
  if (tid < NST) {
    float mag = __expf(-__expf(nulog[tid]));
    float th  = __expf(thlog[tid]);
    lamr = mag * __cosf(th);
    lami = mag * __sinf(th);
  }

  for (int sb = 0; sb < 4; ++sb) {
    int tb = t0 + sb * 16;
    __syncthreads();
    {
      float4 hv = *(const float4*)&h0[((size_t)(b * TSEQ + tb + tg)) * 64 + g * 4];
      float sum = hv.x + hv.y + hv.z + hv.w;
      sum += __shfl_xor(sum, 1); sum += __shfl_xor(sum, 2);
      sum += __shfl_xor(sum, 4); sum += __shfl_xor(sum, 8);
      float mu = sum * (1.f / 64.f);
      float d0 = hv.x - mu, d1 = hv.y - mu, d2 = hv.z - mu, d3 = hv.w - mu;
      float sq = d0 * d0 + d1 * d1 + d2 * d2 + d3 * d3;
      sq += __shfl_xor(sq, 1); sq += __shfl_xor(sq, 2);
      sq += __shfl_xor(sq, 4); sq += __shfl_xor(sq, 8);
      float rs = rsqrtf(sq * (1.f / 64.f) + 1e-5f);
      float4 gv = *(const float4*)&lng[g * 4];
      float4 bv = *(const float4*)&lnb[g * 4];
      float z0 = d0 * rs * gv.x + bv.x;
      float z1 = d1 * rs * gv.y + bv.y;
      float z2 = d2 * rs * gv.z + bv.z;
      float z3 = d3 * rs * gv.w + bv.w;
      *(unsigned*)&zb[tg][g * 4]     = (unsigned)f2b(z0) | ((unsigned)f2b(z1) << 16);
      *(unsigned*)&zb[tg][g * 4 + 2] = (unsigned)f2b(z2) | ((unsigned)f2b(z3) << 16);
    }
    __syncthreads();
    {
      bf16x8 a0 = *(const bf16x8*)((const char*)&zb[0][0] + cl * 144 + q * 16);
      bf16x8 a1 = *(const bf16x8*)((const char*)&zb[0][0] + cl * 144 + 64 + q * 16);
      #pragma unroll
      for (int ti = 0; ti < 4; ++ti) {
        int np0 = (w * 4 + ti) * 16;
        const unsigned short* bp = Bws + (np0 + cl) * 64 + q * 8;
        bf16x8 b0 = *(const bf16x8*)bp;
        bf16x8 b1 = *(const bf16x8*)(bp + 32);
        f32x4 acc = {0.f, 0.f, 0.f, 0.f};
        acc = __builtin_amdgcn_mfma_f32_16x16x32_bf16(a0, b0, acc, 0, 0, 0);
        acc = __builtin_amdgcn_mfma_f32_16x16x32_bf16(a1, b1, acc, 0, 0, 0);
        int np = np0 + cl;
        float gam = __expf(gmlog[np >> 1]);
        ucat[q * 4 + 0][np] = acc[0] * gam;
        ucat[q * 4 + 1][np] = acc[1] * gam;
        ucat[q * 4 + 2][np] = acc[2] * gam;
        ucat[q * 4 + 3][np] = acc[3] * gam;
      }
    }
    __syncthreads();
    if (tid < NST) {
      int n = tid;
      #pragma unroll
      for (int t = 0; t < 16; ++t) {
        float ur = ucat[t][2 * n], ui = ucat[t][2 * n + 1];
        float nr = fmaf(lamr, hr, fmaf(-lami, hi, ur));
        float ni = fmaf(lamr, hi, fmaf(lami, hr, ui));
        hr = nr; hi = ni;
      }
    }
  }
  if (tid < NST) {
    float* cw = carr + ((size_t)(b * NCHUNK + c)) * 256 + 2 * tid;
    cw[0] = hr;
    cw[1] = hi;
  }
}

// ---------------------------------------------------------------------------
// Kernel 4: apply stage s + carry stage s+1 (R8 structure, 64-token chunks).
// Tweaks: h-loads for all 4 sub-tiles hoisted into registers BEFORE the
// lookback (latency overlaps the serial prefix); h0 writeback drains right
// after pass 1 (behind a barrier), overlapping pass-2 compute.
// ---------------------------------------------------------------------------
__launch_bounds__(256)
__global__ void lru_applycarry_kernel(float* __restrict__ h0,
                                      const float* __restrict__ carrin,
                                      float* __restrict__ carrout,
                                      const unsigned short* __restrict__ Bws,
                                      const unsigned short* __restrict__ Cws,
                                      const float* __restrict__ lng,
                                      const float* __restrict__ lnb,
                                      const float* __restrict__ nulog,
                                      const float* __restrict__ thlog,
                                      const float* __restrict__ gmlog,
                                      const float* __restrict__ dskip,
                                      int s, int last,
                                      const unsigned short* __restrict__ Wclst,
                                      const float* __restrict__ bcls,
                                      float* __restrict__ out)
{
  __shared__ float hsm64[64][68];
  __shared__ float hs[16][68];
  __shared__ float zsm[16][68];
  __shared__ __align__(16) unsigned short zb[16][72];
  __shared__ __align__(16) float ucat[16][264];
  __shared__ __align__(16) unsigned short hcb[16][264];

  const int tid = threadIdx.x;
  const int b = blockIdx.x >> 5;
  const int c = blockIdx.x & 31;
  const int t0 = c * CHTOK;
  const int w = tid >> 6, lane = tid & 63;
  const int cl = lane & 15, q = lane >> 4;
  const int tg = tid >> 4, g = tid & 15;

  // hoisted h loads (independent of lookback; latency hidden under it)
  float4 hv4[4];
  #pragma unroll
  for (int sb = 0; sb < 4; ++sb)
    hv4[sb] = *(const float4*)&h0[((size_t)(b * TSEQ + t0 + sb * 16 + tg)) * 64 + g * 4];

  // lambda(s), lam^64, prefix over earlier chunks
  float lamr = 0.f, lami = 0.f, Pr = 0.f, Pi = 0.f;
  if (tid < NST) {
    int n = tid;
    float mag = __expf(-__expf(nulog[s * NST + n]));
    float th  = __expf(thlog[s * NST + n]);
    lamr = mag * __cosf(th);
    lami = mag * __sinf(th);
    float ar = lamr, ai = lami;
    #pragma unroll
    for (int it = 0; it < 6; ++it) {       // lam^64
      float nr = ar * ar - ai * ai;
      float ni = 2.f * ar * ai;
      ar = nr; ai = ni;
    }
    const float* cb = carrin + (size_t)b * NCHUNK * 256 + 2 * n;
    #pragma unroll 4
    for (int j = 0; j < c; ++j) {
      float cr = cb[j * 256];
      float ci = cb[j * 256 + 1];
      float nr = fmaf(ar, Pr, fmaf(-ai, Pi, cr));
      float ni = fmaf(ar, Pi, fmaf(ai, Pr, ci));
      Pr = nr; Pi = ni;
    }
  }

  // ---- pass 1: apply stage s (seeded scan) ----
  float hr = Pr, hi = Pi;
  #pragma unroll
  for (int sb = 0; sb < 4; ++sb) {
    __syncthreads();   // protect LDS reuse across sub-tiles
    {
      float4 hv = hv4[sb];
      hs[tg][g * 4 + 0] = hv.x; hs[tg][g * 4 + 1] = hv.y;
      hs[tg][g * 4 + 2] = hv.z; hs[tg][g * 4 + 3] = hv.w;
      float sum = hv.x + hv.y + hv.z + hv.w;
      sum += __shfl_xor(sum, 1); sum += __shfl_xor(sum, 2);
      sum += __shfl_xor(sum, 4); sum += __shfl_xor(sum, 8);
      float mu = sum * (1.f / 64.f);
      float d0 = hv.x - mu, d1 = hv.y - mu, d2 = hv.z - mu, d3 = hv.w - mu;
      float sq = d0 * d0 + d1 * d1 + d2 * d2 + d3 * d3;
      sq += __shfl_xor(sq, 1); sq += __shfl_xor(sq, 2);
      sq += __shfl_xor(sq, 4); sq += __shfl_xor(sq, 8);
      float rs = rsqrtf(sq * (1.f / 64.f) + 1e-5f);
      float4 gv = *(const float4*)&lng[s * 64 + g * 4];
      float4 bv = *(const float4*)&lnb[s * 64 + g * 4];
      float z0 = d0 * rs * gv.x + bv.x;
      float z1 = d1 * rs * gv.y + bv.y;
      float z2 = d2 * rs * gv.z + bv.z;
      float z3 = d3 * rs * gv.w + bv.w;
      zsm[tg][g * 4 + 0] = z0; zsm[tg][g * 4 + 1] = z1;
      zsm[tg][g * 4 + 2] = z2; zsm[tg][g * 4 + 3] = z3;
      *(unsigned*)&zb[tg][g * 4]     = (unsigned)f2b(z0) | ((unsigned)f2b(z1) << 16);
      *(unsigned*)&zb[tg][g * 4 + 2] = (unsigned)f2b(z2) | ((unsigned)f2b(z3) << 16);
    }
    __syncthreads();
    {
      bf16x8 a0 = *(const bf16x8*)((const char*)&zb[0][0] + cl * 144 + q * 16);
      bf16x8 a1 = *(const bf16x8*)((const char*)&zb[0][0] + cl * 144 + 64 + q * 16);
      const unsigned short* bb = Bws + (size_t)s * NP2 * 64;
      #pragma unroll
      for (int ti = 0; ti < 4; ++ti) {
        int np0 = (w * 4 + ti) * 16;
        const unsigned short* bp = bb + (np0 + cl) * 64 + q * 8;
        bf16x8 b0 = *(const bf16x8*)bp;
        bf16x8 b1 = *(const bf16x8*)(bp + 32);
        f32x4 acc = {0.f, 0.f, 0.f, 0.f};
        acc = __builtin_amdgcn_mfma_f32_16x16x32_bf16(a0, b0, acc, 0, 0, 0);
        acc = __builtin_amdgcn_mfma_f32_16x16x32_bf16(a1, b1, acc, 0, 0, 0);
        int np = np0 + cl;
        float gam = __expf(gmlog[s * NST + (np >> 1)]);
        ucat[q * 4 + 0][np] = acc[0] * gam;
        ucat[q * 4 + 1][np] = acc[1] * gam;
        ucat[q * 4 + 2][np] = acc[2] * gam;
        ucat[q * 4 + 3][np] = acc[3] * gam;
      }
    }
    __syncthreads();
    if (tid < NST) {
      int n = tid;
      #pragma unroll
      for (int t = 0; t < 16; ++t) {
        float ur = ucat[t][2 * n], ui = ucat[t][2 * n + 1];
        float nr = fmaf(lamr, hr, fmaf(-lami, hi, ur));
        float ni = fmaf(lamr, hi, fmaf(lami, hr, ui));
        hr = nr; hi = ni;
        *(unsigned*)&hcb[t][2 * n] = (unsigned)f2b(hr) | ((unsigned)f2b(hi) << 16);
      }
    }
    __syncthreads();
    {
      int d0 = w * 16;
      const unsigned short* cp = Cws + ((size_t)s * 64 + d0 + cl) * NP2 + q * 8;
      f32x4 acc = {0.f, 0.f, 0.f, 0.f};
      #pragma unroll
      for (int ks = 0; ks < 8; ++ks) {
        bf16x8 a  = *(const bf16x8*)((const char*)&hcb[0][0] + cl * 528 + ks * 64 + q * 16);
        bf16x8 cc = *(const bf16x8*)(cp + ks * 32);
        acc = __builtin_amdgcn_mfma_f32_16x16x32_bf16(a, cc, acc, 0, 0, 0);
      }
      int d = d0 + cl;
      float dk = dskip[s * 64 + d];
      #pragma unroll
      for (int r = 0; r < 4; ++r) {
        int t = q * 4 + r;
        hsm64[sb * 16 + t][d] = hs[t][d] + acc[r] + dk * zsm[t][d];
      }
    }
  }
  __syncthreads();   // hsm64 complete

  if (!last) {
    // early h0 writeback: stores drain under pass-2 compute
    #pragma unroll
    for (int sb = 0; sb < 4; ++sb) {
      float4 hv;
      hv.x = hsm64[sb * 16 + tg][g * 4 + 0];
      hv.y = hsm64[sb * 16 + tg][g * 4 + 1];
      hv.z = hsm64[sb * 16 + tg][g * 4 + 2];
      hv.w = hsm64[sb * 16 + tg][g * 4 + 3];
      *(float4*)&h0[((size_t)(b * TSEQ + t0 + sb * 16 + tg)) * 64 + g * 4] = hv;
    }

    // ---- pass 2: carry for stage s+1 from updated h ----
    const int s1 = s + 1;
    float lam2r = 0.f, lam2i = 0.f, h2r = 0.f, h2i = 0.f;
    if (tid < NST) {
      float mag = __expf(-__expf(nulog[s1 * NST + tid]));
      float th  = __expf(thlog[s1 * NST + tid]);
      lam2r = mag * __cosf(th);
      lam2i = mag * __sinf(th);
    }
    for (int sb = 0; sb < 4; ++sb) {
      __syncthreads();
      {
        float4 hv = *(const float4*)&hsm64[sb * 16 + tg][g * 4];
        float sum = hv.x + hv.y + hv.z + hv.w;
        sum += __shfl_xor(sum, 1); sum += __shfl_xor(sum, 2);
        sum += __shfl_xor(sum, 4); sum += __shfl_xor(sum, 8);
        float mu = sum * (1.f / 64.f);
        float d0 = hv.x - mu, d1 = hv.y - mu, d2 = hv.z - mu, d3 = hv.w - mu;
        float sq = d0 * d0 + d1 * d1 + d2 * d2 + d3 * d3;
        sq += __shfl_xor(sq, 1); sq += __shfl_xor(sq, 2);
        sq += __shfl_xor(sq, 4); sq += __shfl_xor(sq, 8);
        float rs = rsqrtf(sq * (1.f / 64.f) + 1e-5f);
        float4 gv = *(const float4*)&lng[s1 * 64 + g * 4];
        float4 bv = *(const float4*)&lnb[s1 * 64 + g * 4];
        float z0 = d0 * rs * gv.x + bv.x;
        float z1 = d1 * rs * gv.y + bv.y;
        float z2 = d2 * rs * gv.z + bv.z;
        float z3 = d3 * rs * gv.w + bv.w;
        *(unsigned*)&zb[tg][g * 4]     = (unsigned)f2b(z0) | ((unsigned)f2b(z1) << 16);
        *(unsigned*)&zb[tg][g * 4 + 2] = (unsigned)f2b(z2) | ((unsigned)f2b(z3) << 16);
      }
      __syncthreads();
      {
        bf16x8 a0 = *(const bf16x8*)((const char*)&zb[0][0] + cl * 144 + q * 16);
        bf16x8 a1 = *(const bf16x8*)((const char*)&zb[0][0] + cl * 144 + 64 + q * 16);
        const unsigned short* bb = Bws + (size_t)s1 * NP2 * 64;
        #pragma unroll
        for (int ti = 0; ti < 4; ++ti) {
          int np0 = (w * 4 + ti) * 16;
          const unsigned short* bp = bb + (np0 + cl) * 64 + q * 8;
          bf16x8 b0 = *(const bf16x8*)bp;
          bf16x8 b1 = *(const bf16x8*)(bp + 32);
          f32x4 acc = {0.f, 0.f, 0.f, 0.f};
          acc = __builtin_amdgcn_mfma_f32_16x16x32_bf16(a0, b0, acc, 0, 0, 0);
          acc = __builtin_amdgcn_mfma_f32_16x16x32_bf16(a1, b1, acc, 0, 0, 0);
          int np = np0 + cl;
          float gam = __expf(gmlog[s1 * NST + (np >> 1)]);
          ucat[q * 4 + 0][np] = acc[0] * gam;
          ucat[q * 4 + 1][np] = acc[1] * gam;
          ucat[q * 4 + 2][np] = acc[2] * gam;
          ucat[q * 4 + 3][np] = acc[3] * gam;
        }
      }
      __syncthreads();
      if (tid < NST) {
        int n = tid;
        #pragma unroll
        for (int t = 0; t < 16; ++t) {
          float ur = ucat[t][2 * n], ui = ucat[t][2 * n + 1];
          float nr = fmaf(lam2r, h2r, fmaf(-lam2i, h2i, ur));
          float ni = fmaf(lam2r, h2i, fmaf(lam2i, h2r, ui));
          h2r = nr; h2i = ni;
        }
      }
    }
    if (tid < NST) {
      float* cw = carrout + ((size_t)(b * NCHUNK + c)) * 256 + 2 * tid;
      cw[0] = h2r;
      cw[1] = h2i;
    }
  } else {
    // ---- classifier: out = h @ W_cls + b_cls ----
    for (int sb = 0; sb < 4; ++sb) {
      int tb = t0 + sb * 16;
      __syncthreads();
      {
        *(unsigned*)&zb[tg][g * 4] =
            (unsigned)f2b(hsm64[sb * 16 + tg][g * 4 + 0]) |
            ((unsigned)f2b(hsm64[sb * 16 + tg][g * 4 + 1]) << 16);
        *(unsigned*)&zb[tg][g * 4 + 2] =
            (unsigned)f2b(hsm64[sb * 16 + tg][g * 4 + 2]) |
            ((unsigned)f2b(hsm64[sb * 16 + tg][g * 4 + 3]) << 16);
      }
      __syncthreads();
      bf16x8 a0 = *(const bf16x8*)((const char*)&zb[0][0] + cl * 144 + q * 16);
      bf16x8 a1 = *(const bf16x8*)((const char*)&zb[0][0] + cl * 144 + 64 + q * 16);
      for (int ti = w; ti < 13; ti += 4) {
        int cls0 = ti * 16;
        const unsigned short* wp = Wclst + (cls0 + cl) * 64 + q * 8;
        bf16x8 b0 = *(const bf16x8*)wp;
        bf16x8 b1 = *(const bf16x8*)(wp + 32);
        f32x4 acc = {0.f, 0.f, 0.f, 0.f};
        acc = __builtin_amdgcn_mfma_f32_16x16x32_bf16(a0, b0, acc, 0, 0, 0);
        acc = __builtin_amdgcn_mfma_f32_16x16x32_bf16(a1, b1, acc, 0, 0, 0);
        int cls = cls0 + cl;
        if (cls < NCLS) {
          float bc = bcls[cls];
          #pragma unroll
          for (int r = 0; r < 4; ++r) {
            int t = q * 4 + r;
            out[((size_t)(b * TSEQ + tb + t)) * NCLS + cls] = acc[r] + bc;
          }
        }
      }
    }
  }
}

// ---------------------------------------------------------------------------
extern "C" void kernel_launch(void* const* d_in, const int* in_sizes, int n_in,
                              void* d_out, int out_size, void* d_ws, size_t ws_size,
                              hipStream_t stream) {
  (void)in_sizes; (void)n_in; (void)out_size; (void)ws_size;
  const float* x     = (const float*)d_in[0];
  const float* ln0g  = (const float*)d_in[1];
  const float* ln0b  = (const float*)d_in[2];
  const float* Wemb  = (const float*)d_in[3];
  const float* bemb  = (const float*)d_in[4];
  const float* lng   = (const float*)d_in[5];
  const float* lnb   = (const float*)d_in[6];
  const float* nulog = (const float*)d_in[7];
  const float* thlog = (const float*)d_in[8];
  const float* gmlog = (const float*)d_in[9];
  const float* Bre   = (const float*)d_in[10];
  const float* Bim   = (const float*)d_in[11];
  const float* Cre   = (const float*)d_in[12];
  const float* Cim   = (const float*)d_in[13];
  const float* dskip = (const float*)d_in[14];
  const float* Wcls  = (const float*)d_in[15];
  const float* bcls  = (const float*)d_in[16];
  float* out = (float*)d_out;

  char* ws = (char*)d_ws;
  // ws layout (bytes):
  //  carrA @0       : 8*32*256*4 = 262144
  //  carrB @262144  : 262144
  //  Bws   @524288  : 20*256*64*2 = 655360
  //  Cws   @1179648 : 655360
  //  Wt    @1835008 : 64*2048*2  = 262144
  //  Wclst @2097152 : 208*64*2   = 26624
  //  h0    @2123776 : 16384*64*4 = 4194304   (end 6318080)
  float* carrA         = (float*)(ws + 0);
  float* carrB         = (float*)(ws + 262144);
  unsigned short* Bws  = (unsigned short*)(ws + 524288);
  unsigned short* Cws  = (unsigned short*)(ws + 1179648);
  unsigned short* Wt   = (unsigned short*)(ws + 1835008);
  unsigned short* Wcl  = (unsigned short*)(ws + 2097152);
  float* h0            = (float*)(ws + 2123776);

  lru_convert_kernel<<<3124, 256, 0, stream>>>(Wemb, Bre, Bim, Cre, Cim, Wcls,
                                               Wt, Bws, Cws, Wcl);
  lru_embed_kernel<<<1024, 256, 0, stream>>>(x, ln0g, ln0b, Wt, bemb, h0);
  lru_carry0_kernel<<<256, 256, 0, stream>>>(h0, Bws, lng, lnb,
                                             nulog, thlog, gmlog, carrA);
  for (int s = 0; s < NSTAGE; ++s) {
    float* cin  = (s & 1) ? carrB : carrA;
    float* cout = (s & 1) ? carrA : carrB;
    lru_applycarry_kernel<<<256, 256, 0, stream>>>(h0, cin, cout, Bws, Cws,
                                                   lng, lnb, nulog, thlog,
                                                   gmlog, dskip, s,
                                                   (s == NSTAGE - 1) ? 1 : 0,
                                                   Wcl, bcls, out);
  }
}